// Round 3
// baseline (188.349 us; speedup 1.0000x reference)
//
#include <hip/hip_runtime.h>

#define NX   32
#define NN   1024          // N = NX*NX
#define NT   9
#define NCH  25            // 9 D + 8 L + 8 U
#define BATCH 2
#define ROWS (BATCH * NCH * NN)   // 51200

typedef float f32x4 __attribute__((ext_vector_type(4)));

// out[b, c, i, k]  (B, 25, N, N) float32
// A_t (5-point stencil + advection, Dirichlet):
//   diag        = kappa^2 + 4
//   A[n,n+1]    = -1 + m1[n]/2   (gx(n) < 31)
//   A[n,n-1]    = -1 - m1[n]/2   (gx(n) > 0)
//   A[n,n+32]   = -1 + m2[n]/2   (gy(n) < 31)
//   A[n,n-32]   = -1 - m2[n]/2   (gy(n) > 0)
// M_t = I + A_t  (t = 1..8),  w[n,t] = 1/tau[n,t]^2
//
// c = 0      : A0^T A0 + 1.05 I
// c = 1..8   : M_c^T diag(w_c) M_c  (+ w_c[i] on diag when c <= 7)
// c = 9..16  : L, t=c-8 :  L[i,k] = -w[k] * M[k,i]
// c = 17..24 : U, t=c-16:  U[i,k] = -w[i] * M[i,k]

__global__ __launch_bounds__(256)
void spde_kernel(const float* __restrict__ kappa,
                 const float* __restrict__ m,
                 const float* __restrict__ tau,
                 float* __restrict__ out) {
    const int tid = threadIdx.x;           // 0..255
    const int k0  = tid * 4;
    const float kap  = kappa[0];
    const float kap2 = kap * kap;

    for (int row = blockIdx.x; row < ROWS; row += gridDim.x) {
        const int b   = (row >= NCH * NN) ? 1 : 0;
        const int rem = row - b * (NCH * NN);
        const int c   = rem >> 10;         // /NN
        const int i   = rem & (NN - 1);    // %NN

        f32x4 v = (f32x4)(0.0f);

        // all non-zeros of row i lie in columns [i-64, i+64]
        if (k0 + 3 >= i - 64 && k0 <= i + 64) {
            const int t = (c == 0) ? 0 : (c <= 8 ? c : (c <= 16 ? c - 8 : c - 16));
            // m[b, ch, n, t]: stride NT in n
            const float* __restrict__ m1 = m + ((size_t)(b * 2 + 0) * NN) * NT + t;
            const float* __restrict__ m2 = m + ((size_t)(b * 2 + 1) * NN) * NT + t;
            const float* __restrict__ tb = tau + ((size_t)b * NN) * NT + t;

            const float diag = ((c == 0) ? 4.0f : 5.0f) + kap2;

            // M_t[n,k] (0 if not a structural neighbor)
            auto Ment = [&](int n, int k) -> float {
                const int d  = k - n;
                const int gx = n & 31, gy = n >> 5;
                if (d == 0)              return diag;
                if (d == 1  && gx < 31)  return -1.0f + 0.5f * m1[n * NT];
                if (d == -1 && gx > 0)   return -1.0f - 0.5f * m1[n * NT];
                if (d == 32 && gy < 31)  return -1.0f + 0.5f * m2[n * NT];
                if (d == -32 && gy > 0)  return -1.0f - 0.5f * m2[n * NT];
                return 0.0f;
            };
            auto W = [&](int n) -> float {
                const float ta = tb[n * NT];
                return 1.0f / (ta * ta);
            };

#pragma unroll
            for (int q = 0; q < 4; ++q) {
                const int k = k0 + q;
                float val = 0.0f;
                if (c >= 17) {                       // U
                    val = -W(i) * Ment(i, k);
                } else if (c >= 9) {                 // L
                    const float e = Ment(k, i);
                    val = (e != 0.0f) ? (-W(k) * e) : 0.0f;
                } else {                             // D: M^T diag(w) M
                    const int gix = i & 31, giy = i >> 5;
                    int nbr[5];
                    int nn = 0;
                    nbr[nn++] = i;
                    if (gix < 31) nbr[nn++] = i + 1;
                    if (gix > 0)  nbr[nn++] = i - 1;
                    if (giy < 31) nbr[nn++] = i + 32;
                    if (giy > 0)  nbr[nn++] = i - 32;
                    float acc = 0.0f;
                    for (int s = 0; s < nn; ++s) {
                        const int n = nbr[s];
                        const float Mni = Ment(n, i);
                        const float Mnk = Ment(n, k);
                        if (Mnk != 0.0f) {
                            const float wn = (c == 0) ? 1.0f : W(n);
                            acc += Mni * wn * Mnk;
                        }
                    }
                    if (k == i) {
                        if (c == 0)      acc += 1.05f;
                        else if (c <= 7) acc += W(i);
                    }
                    val = acc;
                }
                v[q] = val;
            }
        }

        const size_t off = (size_t)row * NN + (size_t)k0;
        __builtin_nontemporal_store(v, reinterpret_cast<f32x4*>(out + off));
    }
}

extern "C" void kernel_launch(void* const* d_in, const int* in_sizes, int n_in,
                              void* d_out, int out_size, void* d_ws, size_t ws_size,
                              hipStream_t stream) {
    const float* kappa = (const float*)d_in[0];
    const float* m     = (const float*)d_in[1];
    // d_in[2] = H (unused)
    const float* tau   = (const float*)d_in[3];
    float* out = (float*)d_out;

    spde_kernel<<<2048, 256, 0, stream>>>(kappa, m, tau, out);
}

// Round 4
// 66.581 us; speedup vs baseline: 2.8289x; 2.8289x over previous
//
#include <hip/hip_runtime.h>

#define NN   1024          // N = 32*32
#define NT   9
#define NCH  25            // 9 D + 8 L + 8 U
#define BATCH 2

typedef float f32x4 __attribute__((ext_vector_type(4)));

// out[b, c, i, k]  (B, 25, N, N) float32
// A_t: diag = kappa^2+4; E_n=-1+m1[n]/2 (gx<31); W_n=-1-m1[n]/2 (gx>0);
//      N_n=-1+m2[n]/2 (gy<31); S_n=-1-m2[n]/2 (gy>0).  M_t = I + A_t.
// w[n,t] = 1/tau[n,t]^2
// c=0     : A0^T A0 + 1.05 I
// c=1..8  : M_t^T diag(w_t) M_t  (+ w_t[i] on diag when c<=7), t=c
// c=9..16 : L_t[i,k] = -w[k] * M[k,i], t=c-8
// c=17..24: U_t[i,k] = -w[i] * M[i,k], t=c-16
//
// For fixed (b,i,c) the row has <=13 nonzeros at offsets
// {-64,-33,-32,-31,-2,-1,0,1,2,31,32,33,64} and the VALUES are wave-uniform.

__global__ __launch_bounds__(256, 8)
void spde_kernel(const float* __restrict__ kappa,
                 const float* __restrict__ m,
                 const float* __restrict__ tau,
                 float* __restrict__ out) {
    const int bid = blockIdx.x;            // 0..2047 = (b, i)
    const int b   = bid >> 10;
    const int i   = bid & (NN - 1);
    const int k0  = threadIdx.x * 4;

    const int gx = i & 31, gy = i >> 5;
    const bool eE = gx < 31, eW = gx > 0, eN = gy < 31, eS = gy > 0;
    const bool eE2 = gx < 30, eW2 = gx > 1, eN2 = gy < 30, eS2 = gy > 1;

    const float kap   = kappa[0];
    const float diagA = kap * kap + 4.0f;
    const float diagM = kap * kap + 5.0f;

    const float* __restrict__ m1b = m   + (size_t)(b * 2 + 0) * NN * NT;
    const float* __restrict__ m2b = m   + (size_t)(b * 2 + 1) * NN * NT;
    const float* __restrict__ tb  = tau + (size_t)b * NN * NT;

    const bool inband = (k0 + 3 >= i - 64) && (k0 <= i + 64);
    const int  d0     = k0 - i;

    float* __restrict__ orow = out + ((size_t)(b * NCH) * NN + i) * NN + k0;

    // ---- selection helper: offsets idx 0..12 <-> {-64,-33,-32,-31,-2,-1,0,1,2,31,32,33,64}
#define SELECT_AND_STORE(C)                                                     \
    {                                                                           \
        f32x4 v = (f32x4)(0.0f);                                                \
        if (inband) {                                                           \
            _Pragma("unroll")                                                   \
            for (int q = 0; q < 4; ++q) {                                       \
                const int d = d0 + q;                                           \
                v[q] = (d==-64)?V0 : (d==-33)?V1 : (d==-32)?V2 : (d==-31)?V3 :  \
                       (d== -2)?V4 : (d== -1)?V5 : (d==  0)?V6 : (d==  1)?V7 :  \
                       (d==  2)?V8 : (d== 31)?V9 : (d== 32)?V10: (d== 33)?V11:  \
                       (d== 64)?V12: 0.0f;                                      \
            }                                                                   \
        }                                                                       \
        *reinterpret_cast<f32x4*>(orow + (size_t)(C) * NN * NN) = v;            \
    }

    // ---------------- D channels: c = 0..8 ----------------
    for (int c = 0; c < 9; ++c) {
        float V0=0,V1=0,V2=0,V3=0,V4=0,V5=0,V6=0,V7=0,V8=0,V9=0,V10=0,V11=0,V12=0;
        if (inband) {
            const int   t  = c;
            const float dg = (c == 0) ? diagA : diagM;
            // n = i
            {
                const float m1i = m1b[i*NT+t], m2i = m2b[i*NT+t];
                float wn = 1.0f;
                if (c != 0) { const float ta = tb[i*NT+t]; wn = 1.0f/(ta*ta); }
                const float a = dg * wn;
                V6 += a * dg;
                if (eE) V7  += a * (-1.0f + 0.5f*m1i);
                if (eW) V5  += a * (-1.0f - 0.5f*m1i);
                if (eN) V10 += a * (-1.0f + 0.5f*m2i);
                if (eS) V2  += a * (-1.0f - 0.5f*m2i);
            }
            if (eE) {   // n = i+1,  M[n,i] = W_n
                const int n = i + 1;
                const float m1n = m1b[n*NT+t], m2n = m2b[n*NT+t];
                float wn = 1.0f;
                if (c != 0) { const float ta = tb[n*NT+t]; wn = 1.0f/(ta*ta); }
                const float Wn = -1.0f - 0.5f*m1n;
                const float a  = wn * Wn;
                V7 += a * dg;                              // d=+1
                V6 += a * Wn;                              // d=0
                if (eE2) V8  += a * (-1.0f + 0.5f*m1n);    // d=+2
                if (eN)  V11 += a * (-1.0f + 0.5f*m2n);    // d=+33
                if (eS)  V3  += a * (-1.0f - 0.5f*m2n);    // d=-31
            }
            if (eW) {   // n = i-1,  M[n,i] = E_n
                const int n = i - 1;
                const float m1n = m1b[n*NT+t], m2n = m2b[n*NT+t];
                float wn = 1.0f;
                if (c != 0) { const float ta = tb[n*NT+t]; wn = 1.0f/(ta*ta); }
                const float En = -1.0f + 0.5f*m1n;
                const float a  = wn * En;
                V5 += a * dg;                              // d=-1
                V6 += a * En;                              // d=0
                if (eW2) V4 += a * (-1.0f - 0.5f*m1n);     // d=-2
                if (eN)  V9 += a * (-1.0f + 0.5f*m2n);     // d=+31
                if (eS)  V1 += a * (-1.0f - 0.5f*m2n);     // d=-33
            }
            if (eN) {   // n = i+32, M[n,i] = S_n
                const int n = i + 32;
                const float m1n = m1b[n*NT+t], m2n = m2b[n*NT+t];
                float wn = 1.0f;
                if (c != 0) { const float ta = tb[n*NT+t]; wn = 1.0f/(ta*ta); }
                const float Sn = -1.0f - 0.5f*m2n;
                const float a  = wn * Sn;
                V10 += a * dg;                             // d=+32
                V6  += a * Sn;                             // d=0
                if (eE)  V11 += a * (-1.0f + 0.5f*m1n);    // d=+33
                if (eW)  V9  += a * (-1.0f - 0.5f*m1n);    // d=+31
                if (eN2) V12 += a * (-1.0f + 0.5f*m2n);    // d=+64
            }
            if (eS) {   // n = i-32, M[n,i] = N_n
                const int n = i - 32;
                const float m1n = m1b[n*NT+t], m2n = m2b[n*NT+t];
                float wn = 1.0f;
                if (c != 0) { const float ta = tb[n*NT+t]; wn = 1.0f/(ta*ta); }
                const float Nn = -1.0f + 0.5f*m2n;
                const float a  = wn * Nn;
                V2 += a * dg;                              // d=-32
                V6 += a * Nn;                              // d=0
                if (eE)  V3 += a * (-1.0f + 0.5f*m1n);     // d=-31
                if (eW)  V1 += a * (-1.0f - 0.5f*m1n);     // d=-33
                if (eS2) V0 += a * (-1.0f - 0.5f*m2n);     // d=-64
            }
            if (c == 0) V6 += 1.05f;
            else if (c <= 7) { const float ta = tb[i*NT+t]; V6 += 1.0f/(ta*ta); }
        }
        SELECT_AND_STORE(c);
    }

    // ---------------- L channels: c = 9..16,  L[i,k] = -w[k]*M[k,i] ----------------
#pragma unroll 2
    for (int c = 9; c < 17; ++c) {
        float V0=0,V1=0,V2=0,V3=0,V4=0,V5=0,V6=0,V7=0,V8=0,V9=0,V10=0,V11=0,V12=0;
        if (inband) {
            const int t = c - 8;
            { const float ta = tb[i*NT+t];      V6  = -(1.0f/(ta*ta)) * diagM; }
            if (eE) { const float ta = tb[(i+1)*NT+t];
                      V7  = -(1.0f/(ta*ta)) * (-1.0f - 0.5f*m1b[(i+1)*NT+t]); }   // W_{i+1}
            if (eW) { const float ta = tb[(i-1)*NT+t];
                      V5  = -(1.0f/(ta*ta)) * (-1.0f + 0.5f*m1b[(i-1)*NT+t]); }   // E_{i-1}
            if (eN) { const float ta = tb[(i+32)*NT+t];
                      V10 = -(1.0f/(ta*ta)) * (-1.0f - 0.5f*m2b[(i+32)*NT+t]); }  // S_{i+32}
            if (eS) { const float ta = tb[(i-32)*NT+t];
                      V2  = -(1.0f/(ta*ta)) * (-1.0f + 0.5f*m2b[(i-32)*NT+t]); }  // N_{i-32}
        }
        SELECT_AND_STORE(c);
    }

    // ---------------- U channels: c = 17..24,  U[i,k] = -w[i]*M[i,k] ----------------
#pragma unroll 2
    for (int c = 17; c < 25; ++c) {
        float V0=0,V1=0,V2=0,V3=0,V4=0,V5=0,V6=0,V7=0,V8=0,V9=0,V10=0,V11=0,V12=0;
        if (inband) {
            const int t = c - 16;
            const float ta = tb[i*NT+t];
            const float wi = 1.0f/(ta*ta);
            V6 = -wi * diagM;
            if (eE) V7  = -wi * (-1.0f + 0.5f*m1b[i*NT+t]);
            if (eW) V5  = -wi * (-1.0f - 0.5f*m1b[i*NT+t]);
            if (eN) V10 = -wi * (-1.0f + 0.5f*m2b[i*NT+t]);
            if (eS) V2  = -wi * (-1.0f - 0.5f*m2b[i*NT+t]);
        }
        SELECT_AND_STORE(c);
    }
#undef SELECT_AND_STORE
}

extern "C" void kernel_launch(void* const* d_in, const int* in_sizes, int n_in,
                              void* d_out, int out_size, void* d_ws, size_t ws_size,
                              hipStream_t stream) {
    const float* kappa = (const float*)d_in[0];
    const float* m     = (const float*)d_in[1];
    // d_in[2] = H (unused)
    const float* tau   = (const float*)d_in[3];
    float* out = (float*)d_out;

    spde_kernel<<<BATCH * NN, 256, 0, stream>>>(kappa, m, tau, out);
}

// Round 5
// 39.222 us; speedup vs baseline: 4.8021x; 1.6975x over previous
//
#include <hip/hip_runtime.h>

#define NN   1024          // N = 32*32
#define NT   9
#define NCH  25            // 9 D + 8 L + 8 U
#define BATCH 2

typedef float f32x4 __attribute__((ext_vector_type(4)));

// out[b, c, i, k]  (B, 25, N, N) float32
// A_t: diag = kappa^2+4; E_n=-1+m1[n]/2 (gx<31); W_n=-1-m1[n]/2 (gx>0);
//      N_n=-1+m2[n]/2 (gy<31); S_n=-1-m2[n]/2 (gy>0).  M_t = I + A_t.
// w[n,t] = 1/tau[n,t]^2
// c=0     : A0^T A0 + 1.05 I
// c=1..8  : M_t^T diag(w_t) M_t  (+ w_t[i] on diag when c<=7), t=c
// c=9..16 : L_t[i,k] = -w[k] * M[k,i], t=c-8
// c=17..24: U_t[i,k] = -w[i] * M[i,k], t=c-16
//
// Row i band offsets (sorted): {-64,-33,-32,-31,-2,-1,0,1,2,31,32,33,64}
// -> slots 0..12; slot 13 is a zero pad. Values are wave-uniform per (b,i,c).

__global__ __launch_bounds__(256, 8)
void spde_kernel(const float* __restrict__ kappa,
                 const float* __restrict__ m,
                 const float* __restrict__ tau,
                 float* __restrict__ out) {
    __shared__ float tab[NCH][14];

    const int bid = blockIdx.x;            // 0..2047 = (b, i)
    const int b   = bid >> 10;
    const int i   = bid & (NN - 1);
    const int tid = threadIdx.x;
    const int k0  = tid * 4;

    const int gx = i & 31, gy = i >> 5;
    const bool eE = gx < 31, eW = gx > 0, eN = gy < 31, eS = gy > 0;
    const bool eE2 = gx < 30, eW2 = gx > 1, eN2 = gy < 30, eS2 = gy > 1;

    const float kap   = kappa[0];
    const float diagA = kap * kap + 4.0f;
    const float diagM = kap * kap + 5.0f;

    // ---------- phase 1: thread c (< 25) fills tab[c][0..13] ----------
    if (tid < NCH) {
        const int c = tid;
        const float* __restrict__ m1b = m   + (size_t)(b * 2 + 0) * NN * NT;
        const float* __restrict__ m2b = m   + (size_t)(b * 2 + 1) * NN * NT;
        const float* __restrict__ tb  = tau + (size_t)b * NN * NT;

        float V0=0,V1=0,V2=0,V3=0,V4=0,V5=0,V6=0,V7=0,V8=0,V9=0,V10=0,V11=0,V12=0;

        if (c < 9) {                       // D: M^T diag(w) M (+ extras)
            const int   t  = c;
            const float dg = (c == 0) ? diagA : diagM;
            {   // n = i
                const float m1i = m1b[i*NT+t], m2i = m2b[i*NT+t];
                float wn = 1.0f;
                if (c != 0) { const float ta = tb[i*NT+t]; wn = 1.0f/(ta*ta); }
                const float a = dg * wn;
                V6 += a * dg;
                if (eE) V7  += a * (-1.0f + 0.5f*m1i);
                if (eW) V5  += a * (-1.0f - 0.5f*m1i);
                if (eN) V10 += a * (-1.0f + 0.5f*m2i);
                if (eS) V2  += a * (-1.0f - 0.5f*m2i);
            }
            if (eE) {   // n = i+1,  M[n,i] = W_n
                const int n = i + 1;
                const float m1n = m1b[n*NT+t], m2n = m2b[n*NT+t];
                float wn = 1.0f;
                if (c != 0) { const float ta = tb[n*NT+t]; wn = 1.0f/(ta*ta); }
                const float Wn = -1.0f - 0.5f*m1n;
                const float a  = wn * Wn;
                V7 += a * dg;
                V6 += a * Wn;
                if (eE2) V8  += a * (-1.0f + 0.5f*m1n);
                if (eN)  V11 += a * (-1.0f + 0.5f*m2n);
                if (eS)  V3  += a * (-1.0f - 0.5f*m2n);
            }
            if (eW) {   // n = i-1,  M[n,i] = E_n
                const int n = i - 1;
                const float m1n = m1b[n*NT+t], m2n = m2b[n*NT+t];
                float wn = 1.0f;
                if (c != 0) { const float ta = tb[n*NT+t]; wn = 1.0f/(ta*ta); }
                const float En = -1.0f + 0.5f*m1n;
                const float a  = wn * En;
                V5 += a * dg;
                V6 += a * En;
                if (eW2) V4 += a * (-1.0f - 0.5f*m1n);
                if (eN)  V9 += a * (-1.0f + 0.5f*m2n);
                if (eS)  V1 += a * (-1.0f - 0.5f*m2n);
            }
            if (eN) {   // n = i+32, M[n,i] = S_n
                const int n = i + 32;
                const float m1n = m1b[n*NT+t], m2n = m2b[n*NT+t];
                float wn = 1.0f;
                if (c != 0) { const float ta = tb[n*NT+t]; wn = 1.0f/(ta*ta); }
                const float Sn = -1.0f - 0.5f*m2n;
                const float a  = wn * Sn;
                V10 += a * dg;
                V6  += a * Sn;
                if (eE)  V11 += a * (-1.0f + 0.5f*m1n);
                if (eW)  V9  += a * (-1.0f - 0.5f*m1n);
                if (eN2) V12 += a * (-1.0f + 0.5f*m2n);
            }
            if (eS) {   // n = i-32, M[n,i] = N_n
                const int n = i - 32;
                const float m1n = m1b[n*NT+t], m2n = m2b[n*NT+t];
                float wn = 1.0f;
                if (c != 0) { const float ta = tb[n*NT+t]; wn = 1.0f/(ta*ta); }
                const float Nn = -1.0f + 0.5f*m2n;
                const float a  = wn * Nn;
                V2 += a * dg;
                V6 += a * Nn;
                if (eE)  V3 += a * (-1.0f + 0.5f*m1n);
                if (eW)  V1 += a * (-1.0f - 0.5f*m1n);
                if (eS2) V0 += a * (-1.0f - 0.5f*m2n);
            }
            if (c == 0) V6 += 1.05f;
            else if (c <= 7) { const float ta = tb[i*NT+t]; V6 += 1.0f/(ta*ta); }
        } else if (c < 17) {               // L: L[i,k] = -w[k]*M[k,i]
            const int t = c - 8;
            { const float ta = tb[i*NT+t];      V6  = -(1.0f/(ta*ta)) * diagM; }
            if (eE) { const float ta = tb[(i+1)*NT+t];
                      V7  = -(1.0f/(ta*ta)) * (-1.0f - 0.5f*m1b[(i+1)*NT+t]); }
            if (eW) { const float ta = tb[(i-1)*NT+t];
                      V5  = -(1.0f/(ta*ta)) * (-1.0f + 0.5f*m1b[(i-1)*NT+t]); }
            if (eN) { const float ta = tb[(i+32)*NT+t];
                      V10 = -(1.0f/(ta*ta)) * (-1.0f - 0.5f*m2b[(i+32)*NT+t]); }
            if (eS) { const float ta = tb[(i-32)*NT+t];
                      V2  = -(1.0f/(ta*ta)) * (-1.0f + 0.5f*m2b[(i-32)*NT+t]); }
        } else {                            // U: U[i,k] = -w[i]*M[i,k]
            const int t = c - 16;
            const float ta = tb[i*NT+t];
            const float wi = 1.0f/(ta*ta);
            V6 = -wi * diagM;
            if (eE) V7  = -wi * (-1.0f + 0.5f*m1b[i*NT+t]);
            if (eW) V5  = -wi * (-1.0f - 0.5f*m1b[i*NT+t]);
            if (eN) V10 = -wi * (-1.0f + 0.5f*m2b[i*NT+t]);
            if (eS) V2  = -wi * (-1.0f - 0.5f*m2b[i*NT+t]);
        }

        tab[c][0]=V0;  tab[c][1]=V1;  tab[c][2]=V2;  tab[c][3]=V3;
        tab[c][4]=V4;  tab[c][5]=V5;  tab[c][6]=V6;  tab[c][7]=V7;
        tab[c][8]=V8;  tab[c][9]=V9;  tab[c][10]=V10; tab[c][11]=V11;
        tab[c][12]=V12; tab[c][13]=0.0f;
    }

    // ---------- per-thread slot byte offsets (fixed across channels) ----------
    const int d0 = k0 - i;
    int off0, off1, off2, off3;
    {
        auto slotByte = [](int d) -> int {
            int s = 52;                         // pad (zero)
            s = (d==-64)? 0  : s;  s = (d==-33)? 4  : s;
            s = (d==-32)? 8  : s;  s = (d==-31)? 12 : s;
            s = (d== -2)? 16 : s;  s = (d== -1)? 20 : s;
            s = (d==  0)? 24 : s;  s = (d==  1)? 28 : s;
            s = (d==  2)? 32 : s;  s = (d== 31)? 36 : s;
            s = (d== 32)? 40 : s;  s = (d== 33)? 44 : s;
            s = (d== 64)? 48 : s;
            return s;
        };
        off0 = slotByte(d0);     off1 = slotByte(d0 + 1);
        off2 = slotByte(d0 + 2); off3 = slotByte(d0 + 3);
    }

    __syncthreads();

    // ---------- phase 2: pure streaming — all 256 threads identical ----------
    const char* tb0 = (const char*)&tab[0][0];
    const char* a0 = tb0 + off0;
    const char* a1 = tb0 + off1;
    const char* a2 = tb0 + off2;
    const char* a3 = tb0 + off3;

    float* __restrict__ orow = out + ((size_t)(b * NCH) * NN + i) * NN + k0;

#pragma unroll
    for (int c = 0; c < NCH; ++c) {
        f32x4 v;
        v[0] = *(const float*)(a0 + c * 56);
        v[1] = *(const float*)(a1 + c * 56);
        v[2] = *(const float*)(a2 + c * 56);
        v[3] = *(const float*)(a3 + c * 56);
        *reinterpret_cast<f32x4*>(orow + (size_t)c * NN * NN) = v;
    }
}

extern "C" void kernel_launch(void* const* d_in, const int* in_sizes, int n_in,
                              void* d_out, int out_size, void* d_ws, size_t ws_size,
                              hipStream_t stream) {
    const float* kappa = (const float*)d_in[0];
    const float* m     = (const float*)d_in[1];
    // d_in[2] = H (unused)
    const float* tau   = (const float*)d_in[3];
    float* out = (float*)d_out;

    spde_kernel<<<BATCH * NN, 256, 0, stream>>>(kappa, m, tau, out);
}